// Round 1
// baseline (569.896 us; speedup 1.0000x reference)
//
#include <hip/hip_runtime.h>

typedef __attribute__((ext_vector_type(8))) short short8;
typedef __attribute__((ext_vector_type(4))) float f32x4;
typedef __attribute__((ext_vector_type(4))) unsigned short u16x4;

__device__ inline unsigned short f2bf(float x) {
    union { float f; unsigned u; } v; v.f = x;
    unsigned r = v.u + 0x7fffu + ((v.u >> 16) & 1u);
    return (unsigned short)(r >> 16);
}
__device__ inline float bf2f(unsigned short h) {
    union { unsigned u; float f; } v; v.u = ((unsigned)h) << 16;
    return v.f;
}

// C = A * B^T  (A: [M][K] lda, Bt: [N][K] ldb, C: [M][N] ldc), optional C2 mirror.
// 128x128 tile, BK=32, 4 waves each 64x64 via 4x4 grid of 16x16x32 bf16 MFMA.
// SPLIT: 3-term hi/lo bf16 split for ~fp32 precision.
template<bool SPLIT>
__global__ __launch_bounds__(256, 2)
void gemm_bt(const float* __restrict__ A, long sA, int lda,
             const float* __restrict__ B, long sB, int ldb,
             float* __restrict__ C, long sC, int ldc,
             float* __restrict__ C2, long sC2, int ldc2,
             int K)
{
    constexpr int LDS_S = 40;  // 32 + 8 pad (bf16 elems) to break bank conflicts
    extern __shared__ unsigned short lds[];
    unsigned short* Ah = lds;
    unsigned short* Bh = lds + 128 * LDS_S;
    unsigned short* Al = SPLIT ? (lds + 2 * 128 * LDS_S) : nullptr;
    unsigned short* Bl = SPLIT ? (lds + 3 * 128 * LDS_S) : nullptr;

    const int tid = threadIdx.x;
    const int bz = blockIdx.z;
    A += (long)bz * sA; B += (long)bz * sB; C += (long)bz * sC;
    if (C2) C2 += (long)bz * sC2;
    const long m0 = (long)blockIdx.x * 128;
    const long n0 = (long)blockIdx.y * 128;

    const int lane = tid & 63, wave = tid >> 6;
    const int wm = (wave >> 1) * 64, wn = (wave & 1) * 64;
    const int fr = lane & 15, kq = lane >> 4, k0 = kq * 8;

    const int sc4 = (tid & 7) * 4;  // staging col (floats), 8 float4 per 32-wide row
    const int sr  = tid >> 3;       // staging row base 0..31

    f32x4 acc[4][4] = {};

    for (int kb = 0; kb < K; kb += 32) {
        // ---- stage A and Bt tiles (128 rows x 32 cols each), fp32 -> bf16 hi(/lo)
        #pragma unroll
        for (int p = 0; p < 4; ++p) {
            const int row = p * 32 + sr;
            const float4 va = *(const float4*)(A + (m0 + row) * lda + kb + sc4);
            const float4 vb = *(const float4*)(B + (n0 + row) * ldb + kb + sc4);
            u16x4 ah; ah[0] = f2bf(va.x); ah[1] = f2bf(va.y); ah[2] = f2bf(va.z); ah[3] = f2bf(va.w);
            u16x4 bh; bh[0] = f2bf(vb.x); bh[1] = f2bf(vb.y); bh[2] = f2bf(vb.z); bh[3] = f2bf(vb.w);
            *(u16x4*)(Ah + row * LDS_S + sc4) = ah;
            *(u16x4*)(Bh + row * LDS_S + sc4) = bh;
            if constexpr (SPLIT) {
                u16x4 al; al[0] = f2bf(va.x - bf2f(ah[0])); al[1] = f2bf(va.y - bf2f(ah[1]));
                          al[2] = f2bf(va.z - bf2f(ah[2])); al[3] = f2bf(va.w - bf2f(ah[3]));
                u16x4 bl; bl[0] = f2bf(vb.x - bf2f(bh[0])); bl[1] = f2bf(vb.y - bf2f(bh[1]));
                          bl[2] = f2bf(vb.z - bf2f(bh[2])); bl[3] = f2bf(vb.w - bf2f(bh[3]));
                *(u16x4*)(Al + row * LDS_S + sc4) = al;
                *(u16x4*)(Bl + row * LDS_S + sc4) = bl;
            }
        }
        __syncthreads();

        // ---- fragments: A[m=lane&15][k=kq*8+j], Bt[n=lane&15][k=kq*8+j]
        short8 af[4], bfr[4], alf[4], blf[4];
        #pragma unroll
        for (int t = 0; t < 4; ++t) {
            af[t]  = *(const short8*)(Ah + (wm + t * 16 + fr) * LDS_S + k0);
            bfr[t] = *(const short8*)(Bh + (wn + t * 16 + fr) * LDS_S + k0);
            if constexpr (SPLIT) {
                alf[t] = *(const short8*)(Al + (wm + t * 16 + fr) * LDS_S + k0);
                blf[t] = *(const short8*)(Bl + (wn + t * 16 + fr) * LDS_S + k0);
            }
        }
        #pragma unroll
        for (int mt = 0; mt < 4; ++mt)
            #pragma unroll
            for (int nt = 0; nt < 4; ++nt) {
                acc[mt][nt] = __builtin_amdgcn_mfma_f32_16x16x32_bf16(af[mt], bfr[nt], acc[mt][nt], 0, 0, 0);
                if constexpr (SPLIT) {
                    acc[mt][nt] = __builtin_amdgcn_mfma_f32_16x16x32_bf16(alf[mt], bfr[nt], acc[mt][nt], 0, 0, 0);
                    acc[mt][nt] = __builtin_amdgcn_mfma_f32_16x16x32_bf16(af[mt], blf[nt], acc[mt][nt], 0, 0, 0);
                }
            }
        __syncthreads();
    }

    // ---- epilogue: C row = quad*4+i, col = lane&15 (verified C/D layout)
    #pragma unroll
    for (int mt = 0; mt < 4; ++mt) {
        const long rowb = m0 + wm + mt * 16 + kq * 4;
        #pragma unroll
        for (int nt = 0; nt < 4; ++nt) {
            const long col = n0 + wn + nt * 16 + fr;
            #pragma unroll
            for (int i = 0; i < 4; ++i) {
                C[(rowb + i) * ldc + col] = acc[mt][nt][i];
                if (C2) C2[(rowb + i) * ldc2 + col] = acc[mt][nt][i];
            }
        }
    }
}

// Row softmax over 512 cols, in place. One wave per row, 4 rows per block.
__global__ __launch_bounds__(256)
void softmax_rows(float* __restrict__ S)
{
    const int wave = threadIdx.x >> 6, lane = threadIdx.x & 63;
    const long row = (long)blockIdx.x * 4 + wave;
    float* p = S + row * 512 + lane * 8;
    float4 v0 = *(float4*)p;
    float4 v1 = *(float4*)(p + 4);
    float m = fmaxf(fmaxf(fmaxf(v0.x, v0.y), fmaxf(v0.z, v0.w)),
                    fmaxf(fmaxf(v1.x, v1.y), fmaxf(v1.z, v1.w)));
    #pragma unroll
    for (int off = 32; off > 0; off >>= 1) m = fmaxf(m, __shfl_xor(m, off));
    v0.x = __expf(v0.x - m); v0.y = __expf(v0.y - m);
    v0.z = __expf(v0.z - m); v0.w = __expf(v0.w - m);
    v1.x = __expf(v1.x - m); v1.y = __expf(v1.y - m);
    v1.z = __expf(v1.z - m); v1.w = __expf(v1.w - m);
    float s = v0.x + v0.y + v0.z + v0.w + v1.x + v1.y + v1.z + v1.w;
    #pragma unroll
    for (int off = 32; off > 0; off >>= 1) s += __shfl_xor(s, off);
    const float inv = 1.0f / s;
    v0.x *= inv; v0.y *= inv; v0.z *= inv; v0.w *= inv;
    v1.x *= inv; v1.y *= inv; v1.z *= inv; v1.w *= inv;
    *(float4*)p = v0;
    *(float4*)(p + 4) = v1;
}

// sentT[b][e][n] = sent[b][n][e]   (sent: 8 x 512 x 1024)
__global__ void transpose_bn(const float* __restrict__ in, float* __restrict__ out)
{
    __shared__ float tile[32][33];
    const int b = blockIdx.z;
    const int n0 = blockIdx.x * 32, e0 = blockIdx.y * 32;
    const float* src = in + (long)b * 512 * 1024;
    float* dst = out + (long)b * 1024 * 512;
    const int tx = threadIdx.x, ty = threadIdx.y;
    for (int i = ty; i < 32; i += 8)
        tile[i][tx] = src[(long)(n0 + i) * 1024 + e0 + tx];
    __syncthreads();
    for (int i = ty; i < 32; i += 8)
        dst[(long)(e0 + i) * 512 + n0 + tx] = tile[tx][i];
}

extern "C" void kernel_launch(void* const* d_in, const int* in_sizes, int n_in,
                              void* d_out, int out_size, void* d_ws, size_t ws_size,
                              hipStream_t stream)
{
    const float* word = (const float*)d_in[0];  // (8,2048,1024)
    const float* sent = (const float*)d_in[1];  // (8,512,1024)
    const float* W    = (const float*)d_in[2];  // (1024,1024)
    float* out  = (float*)d_out;
    float* comb = out;                              // (8,2048,2048)
    float* gout = out + (long)8 * 2048 * 2048;      // (8,2048,1024)
    float* scores = (float*)d_ws;                   // (8,2048,512) = 32 MB
    float* sentT  = scores + (long)8 * 2048 * 512;  // (8,1024,512) = 16 MB

    const size_t lds_split  = 4 * 128 * 40 * sizeof(unsigned short);  // 40 KiB
    const size_t lds_single = 2 * 128 * 40 * sizeof(unsigned short);  // 20 KiB

    // sent^T for GEMM3's B-operand layout
    transpose_bn<<<dim3(16, 32, 8), dim3(32, 8), 0, stream>>>(sent, sentT);

    // GEMM1 (split): w = word @ W^T  -> combination[:, :, 0:1024]
    gemm_bt<true><<<dim3(128, 8, 1), 256, lds_split, stream>>>(
        word, 0L, 1024, W, 0L, 1024,
        comb, 0L, 2048, nullptr, 0L, 0, 1024);

    // GEMM2 (split): scores = w @ sent^T   (per batch)
    gemm_bt<true><<<dim3(16, 4, 8), 256, lds_split, stream>>>(
        comb, (long)2048 * 2048, 2048, sent, (long)512 * 1024, 1024,
        scores, (long)2048 * 512, 512, nullptr, 0L, 0, 1024);

    // softmax over last dim (512), in place
    softmax_rows<<<4096, 256, 0, stream>>>(scores);

    // GEMM3 (plain bf16): g = att @ sent = att @ (sentT)^T
    //   -> g output AND combination[:, :, 1024:2048]
    gemm_bt<false><<<dim3(16, 8, 8), 256, lds_single, stream>>>(
        scores, (long)2048 * 512, 512, sentT, (long)1024 * 512, 512,
        gout, (long)2048 * 1024, 1024, comb + 1024, (long)2048 * 2048, 2048, 512);
}

// Round 2
// 475.736 us; speedup vs baseline: 1.1979x; 1.1979x over previous
//
#include <hip/hip_runtime.h>

typedef __attribute__((ext_vector_type(8))) short short8;
typedef __attribute__((ext_vector_type(4))) float f32x4;
typedef __attribute__((ext_vector_type(4))) unsigned short u16x4;

typedef const __attribute__((address_space(1))) void* gas_t;
typedef __attribute__((address_space(3))) void* las_t;

__device__ inline unsigned short f2bf(float x) {
    union { float f; unsigned u; } v; v.f = x;
    unsigned r = v.u + 0x7fffu + ((v.u >> 16) & 1u);
    return (unsigned short)(r >> 16);
}
__device__ inline float bf2f(unsigned short h) {
    union { unsigned u; float f; } v; v.u = ((unsigned)h) << 16;
    return v.f;
}

// ============================ FAST PATH =====================================
// Pre-convert fp32 -> bf16 hi/lo, then GEMMs stage bf16 via global_load_lds
// (m97 structure: contiguous unpadded LDS rows, width=16 DMA).

__global__ __launch_bounds__(256)
void convert_hl(const float* __restrict__ x, unsigned short* __restrict__ h,
                unsigned short* __restrict__ l)
{
    const long i = ((long)blockIdx.x * 256 + threadIdx.x) * 4;
    const float4 v = *(const float4*)(x + i);
    u16x4 hh, ll;
    hh[0] = f2bf(v.x); hh[1] = f2bf(v.y); hh[2] = f2bf(v.z); hh[3] = f2bf(v.w);
    ll[0] = f2bf(v.x - bf2f(hh[0])); ll[1] = f2bf(v.y - bf2f(hh[1]));
    ll[2] = f2bf(v.z - bf2f(hh[2])); ll[3] = f2bf(v.w - bf2f(hh[3]));
    *(u16x4*)(h + i) = hh;
    *(u16x4*)(l + i) = ll;
}

// sentT_h[b][e][n] = bf16(sent[b][n][e])   (sent: 8 x 512 x 1024 fp32)
__global__ void transpose_conv(const float* __restrict__ in, unsigned short* __restrict__ out)
{
    __shared__ float tile[32][33];
    const int b = blockIdx.z;
    const int n0 = blockIdx.x * 32, e0 = blockIdx.y * 32;
    const float* src = in + (long)b * 512 * 1024;
    unsigned short* dst = out + (long)b * 1024 * 512;
    const int tx = threadIdx.x, ty = threadIdx.y;
    for (int i = ty; i < 32; i += 8)
        tile[i][tx] = src[(long)(n0 + i) * 1024 + e0 + tx];
    __syncthreads();
    for (int i = ty; i < 32; i += 8)
        dst[(long)(e0 + i) * 512 + n0 + tx] = f2bf(tile[tx][i]);
}

// Row softmax over 512 cols: read fp32 scores, write bf16 att.
__global__ __launch_bounds__(256)
void softmax_bf16(const float* __restrict__ S, unsigned short* __restrict__ att)
{
    const int wave = threadIdx.x >> 6, lane = threadIdx.x & 63;
    const long row = (long)blockIdx.x * 4 + wave;
    const float* p = S + row * 512 + lane * 8;
    float4 v0 = *(const float4*)p;
    float4 v1 = *(const float4*)(p + 4);
    float m = fmaxf(fmaxf(fmaxf(v0.x, v0.y), fmaxf(v0.z, v0.w)),
                    fmaxf(fmaxf(v1.x, v1.y), fmaxf(v1.z, v1.w)));
    #pragma unroll
    for (int off = 32; off > 0; off >>= 1) m = fmaxf(m, __shfl_xor(m, off));
    v0.x = __expf(v0.x - m); v0.y = __expf(v0.y - m);
    v0.z = __expf(v0.z - m); v0.w = __expf(v0.w - m);
    v1.x = __expf(v1.x - m); v1.y = __expf(v1.y - m);
    v1.z = __expf(v1.z - m); v1.w = __expf(v1.w - m);
    float s = v0.x + v0.y + v0.z + v0.w + v1.x + v1.y + v1.z + v1.w;
    #pragma unroll
    for (int off = 32; off > 0; off >>= 1) s += __shfl_xor(s, off);
    const float inv = 1.0f / s;
    u16x4 a0, a1;
    a0[0] = f2bf(v0.x * inv); a0[1] = f2bf(v0.y * inv);
    a0[2] = f2bf(v0.z * inv); a0[3] = f2bf(v0.w * inv);
    a1[0] = f2bf(v1.x * inv); a1[1] = f2bf(v1.y * inv);
    a1[2] = f2bf(v1.z * inv); a1[3] = f2bf(v1.w * inv);
    unsigned short* o = att + row * 512 + lane * 8;
    *(u16x4*)o = a0;
    *(u16x4*)(o + 4) = a1;
}

enum { M_PLAIN = 0, M_SPLIT_DMA = 1, M_SPLIT_ACONV = 2 };

// C = A * B^T. 128x128 tile, BK=32, 4 waves, 4x4 grid of 16x16x32 bf16 MFMA.
// LDS rows are contiguous 32 bf16 (64 B) — required by global_load_lds
// (wave-uniform base + lane*16, no padding allowed).
template<int MODE>
__global__ __launch_bounds__(256, 2)
void gemm_fast(const void* __restrict__ Aptr,            // bf16-hi (DMA) or fp32 (ACONV)
               const unsigned short* __restrict__ Alo,   // bf16-lo (SPLIT_DMA only)
               long sA, int lda,
               const unsigned short* __restrict__ Bhi,
               const unsigned short* __restrict__ Blo,   // SPLIT only
               long sB, int ldb,
               float* __restrict__ C, long sC, int ldc,
               float* __restrict__ C2, long sC2, int ldc2,
               int K)
{
    constexpr bool SPLIT = (MODE != M_PLAIN);
    extern __shared__ unsigned short lds[];
    unsigned short* AhL = lds;                // 128*32 bf16 = 8 KB
    unsigned short* BhL = lds + 128 * 32;
    unsigned short* AlL = SPLIT ? lds + 2 * 128 * 32 : nullptr;
    unsigned short* BlL = SPLIT ? lds + 3 * 128 * 32 : nullptr;

    const int tid = threadIdx.x;
    const long bz = blockIdx.z;
    const long m0 = (long)blockIdx.x * 128;
    const long n0 = (long)blockIdx.y * 128;

    const int lane = tid & 63, wave = tid >> 6;
    const int wm = (wave >> 1) * 64, wn = (wave & 1) * 64;
    const int fr = lane & 15, kq = lane >> 4, k0 = kq * 8;

    // DMA staging coords: lane covers row (lane>>2), 16B chunk (lane&3)
    const int drow = lane >> 2, dcol = (lane & 3) * 8;

    const unsigned short* Bh = Bhi + bz * sB;
    const unsigned short* Bl = SPLIT ? (Blo + bz * sB) : nullptr;

    f32x4 acc[4][4] = {};

    for (int kb = 0; kb < K; kb += 32) {
        // ---- stage A tile(s)
        if constexpr (MODE != M_SPLIT_ACONV) {
            const unsigned short* Ah = (const unsigned short*)Aptr + bz * sA;
            #pragma unroll
            for (int r = 0; r < 2; ++r) {
                const int rb = r * 64 + wave * 16;
                __builtin_amdgcn_global_load_lds(
                    (gas_t)(Ah + (m0 + rb + drow) * (long)lda + kb + dcol),
                    (las_t)(AhL + rb * 32), 16, 0, 0);
                if constexpr (MODE == M_SPLIT_DMA) {
                    const unsigned short* Al = Alo + bz * sA;
                    __builtin_amdgcn_global_load_lds(
                        (gas_t)(Al + (m0 + rb + drow) * (long)lda + kb + dcol),
                        (las_t)(AlL + rb * 32), 16, 0, 0);
                }
            }
        } else {
            const float* Af = (const float*)Aptr + bz * sA;
            const int sr = tid >> 3, c4 = (tid & 7) * 4;
            #pragma unroll
            for (int p = 0; p < 4; ++p) {
                const int row = p * 32 + sr;
                const float4 va = *(const float4*)(Af + (m0 + row) * (long)lda + kb + c4);
                u16x4 h, l;
                h[0] = f2bf(va.x); h[1] = f2bf(va.y); h[2] = f2bf(va.z); h[3] = f2bf(va.w);
                l[0] = f2bf(va.x - bf2f(h[0])); l[1] = f2bf(va.y - bf2f(h[1]));
                l[2] = f2bf(va.z - bf2f(h[2])); l[3] = f2bf(va.w - bf2f(h[3]));
                *(u16x4*)(AhL + row * 32 + c4) = h;
                *(u16x4*)(AlL + row * 32 + c4) = l;
            }
        }
        // ---- stage B tile(s) (always DMA)
        #pragma unroll
        for (int r = 0; r < 2; ++r) {
            const int rb = r * 64 + wave * 16;
            __builtin_amdgcn_global_load_lds(
                (gas_t)(Bh + (n0 + rb + drow) * (long)ldb + kb + dcol),
                (las_t)(BhL + rb * 32), 16, 0, 0);
            if constexpr (SPLIT) {
                __builtin_amdgcn_global_load_lds(
                    (gas_t)(Bl + (n0 + rb + drow) * (long)ldb + kb + dcol),
                    (las_t)(BlL + rb * 32), 16, 0, 0);
            }
        }
        __syncthreads();

        // ---- fragments: A[m=lane&15][k=kq*8+j], Bt[n=lane&15][k=kq*8+j]
        short8 af[4], bfr[4], alf[4], blf[4];
        #pragma unroll
        for (int t = 0; t < 4; ++t) {
            af[t]  = *(const short8*)(AhL + (wm + t * 16 + fr) * 32 + k0);
            bfr[t] = *(const short8*)(BhL + (wn + t * 16 + fr) * 32 + k0);
            if constexpr (SPLIT) {
                alf[t] = *(const short8*)(AlL + (wm + t * 16 + fr) * 32 + k0);
                blf[t] = *(const short8*)(BlL + (wn + t * 16 + fr) * 32 + k0);
            }
        }
        #pragma unroll
        for (int mt = 0; mt < 4; ++mt)
            #pragma unroll
            for (int nt = 0; nt < 4; ++nt) {
                acc[mt][nt] = __builtin_amdgcn_mfma_f32_16x16x32_bf16(af[mt], bfr[nt], acc[mt][nt], 0, 0, 0);
                if constexpr (SPLIT) {
                    acc[mt][nt] = __builtin_amdgcn_mfma_f32_16x16x32_bf16(alf[mt], bfr[nt], acc[mt][nt], 0, 0, 0);
                    acc[mt][nt] = __builtin_amdgcn_mfma_f32_16x16x32_bf16(af[mt], blf[nt], acc[mt][nt], 0, 0, 0);
                }
            }
        __syncthreads();
    }

    // ---- epilogue: C row = kq*4+i, col = lane&15 (verified C/D layout)
    float* Cb = C + bz * sC;
    float* C2b = C2 ? C2 + bz * sC2 : nullptr;
    #pragma unroll
    for (int mt = 0; mt < 4; ++mt) {
        const long rowb = m0 + wm + mt * 16 + kq * 4;
        #pragma unroll
        for (int nt = 0; nt < 4; ++nt) {
            const long col = n0 + wn + nt * 16 + fr;
            #pragma unroll
            for (int i = 0; i < 4; ++i) {
                Cb[(rowb + i) * ldc + col] = acc[mt][nt][i];
                if (C2b) C2b[(rowb + i) * ldc2 + col] = acc[mt][nt][i];
            }
        }
    }
}

// ============================ FALLBACK PATH (round-1) ========================

template<bool SPLIT>
__global__ __launch_bounds__(256, 2)
void gemm_bt(const float* __restrict__ A, long sA, int lda,
             const float* __restrict__ B, long sB, int ldb,
             float* __restrict__ C, long sC, int ldc,
             float* __restrict__ C2, long sC2, int ldc2,
             int K)
{
    constexpr int LDS_S = 40;
    extern __shared__ unsigned short lds[];
    unsigned short* Ah = lds;
    unsigned short* Bh = lds + 128 * LDS_S;
    unsigned short* Al = SPLIT ? (lds + 2 * 128 * LDS_S) : nullptr;
    unsigned short* Bl = SPLIT ? (lds + 3 * 128 * LDS_S) : nullptr;

    const int tid = threadIdx.x;
    const int bz = blockIdx.z;
    A += (long)bz * sA; B += (long)bz * sB; C += (long)bz * sC;
    if (C2) C2 += (long)bz * sC2;
    const long m0 = (long)blockIdx.x * 128;
    const long n0 = (long)blockIdx.y * 128;

    const int lane = tid & 63, wave = tid >> 6;
    const int wm = (wave >> 1) * 64, wn = (wave & 1) * 64;
    const int fr = lane & 15, kq = lane >> 4, k0 = kq * 8;
    const int sc4 = (tid & 7) * 4;
    const int sr  = tid >> 3;

    f32x4 acc[4][4] = {};

    for (int kb = 0; kb < K; kb += 32) {
        #pragma unroll
        for (int p = 0; p < 4; ++p) {
            const int row = p * 32 + sr;
            const float4 va = *(const float4*)(A + (m0 + row) * lda + kb + sc4);
            const float4 vb = *(const float4*)(B + (n0 + row) * ldb + kb + sc4);
            u16x4 ah; ah[0] = f2bf(va.x); ah[1] = f2bf(va.y); ah[2] = f2bf(va.z); ah[3] = f2bf(va.w);
            u16x4 bh; bh[0] = f2bf(vb.x); bh[1] = f2bf(vb.y); bh[2] = f2bf(vb.z); bh[3] = f2bf(vb.w);
            *(u16x4*)(Ah + row * LDS_S + sc4) = ah;
            *(u16x4*)(Bh + row * LDS_S + sc4) = bh;
            if constexpr (SPLIT) {
                u16x4 al; al[0] = f2bf(va.x - bf2f(ah[0])); al[1] = f2bf(va.y - bf2f(ah[1]));
                          al[2] = f2bf(va.z - bf2f(ah[2])); al[3] = f2bf(va.w - bf2f(ah[3]));
                u16x4 bl; bl[0] = f2bf(vb.x - bf2f(bh[0])); bl[1] = f2bf(vb.y - bf2f(bh[1]));
                          bl[2] = f2bf(vb.z - bf2f(bh[2])); bl[3] = f2bf(vb.w - bf2f(bh[3]));
                *(u16x4*)(Al + row * LDS_S + sc4) = al;
                *(u16x4*)(Bl + row * LDS_S + sc4) = bl;
            }
        }
        __syncthreads();

        short8 af[4], bfr[4], alf[4], blf[4];
        #pragma unroll
        for (int t = 0; t < 4; ++t) {
            af[t]  = *(const short8*)(Ah + (wm + t * 16 + fr) * LDS_S + k0);
            bfr[t] = *(const short8*)(Bh + (wn + t * 16 + fr) * LDS_S + k0);
            if constexpr (SPLIT) {
                alf[t] = *(const short8*)(Al + (wm + t * 16 + fr) * LDS_S + k0);
                blf[t] = *(const short8*)(Bl + (wn + t * 16 + fr) * LDS_S + k0);
            }
        }
        #pragma unroll
        for (int mt = 0; mt < 4; ++mt)
            #pragma unroll
            for (int nt = 0; nt < 4; ++nt) {
                acc[mt][nt] = __builtin_amdgcn_mfma_f32_16x16x32_bf16(af[mt], bfr[nt], acc[mt][nt], 0, 0, 0);
                if constexpr (SPLIT) {
                    acc[mt][nt] = __builtin_amdgcn_mfma_f32_16x16x32_bf16(alf[mt], bfr[nt], acc[mt][nt], 0, 0, 0);
                    acc[mt][nt] = __builtin_amdgcn_mfma_f32_16x16x32_bf16(af[mt], blf[nt], acc[mt][nt], 0, 0, 0);
                }
            }
        __syncthreads();
    }

    #pragma unroll
    for (int mt = 0; mt < 4; ++mt) {
        const long rowb = m0 + wm + mt * 16 + kq * 4;
        #pragma unroll
        for (int nt = 0; nt < 4; ++nt) {
            const long col = n0 + wn + nt * 16 + fr;
            #pragma unroll
            for (int i = 0; i < 4; ++i) {
                C[(rowb + i) * ldc + col] = acc[mt][nt][i];
                if (C2) C2[(rowb + i) * ldc2 + col] = acc[mt][nt][i];
            }
        }
    }
}

__global__ __launch_bounds__(256)
void softmax_rows(float* __restrict__ S)
{
    const int wave = threadIdx.x >> 6, lane = threadIdx.x & 63;
    const long row = (long)blockIdx.x * 4 + wave;
    float* p = S + row * 512 + lane * 8;
    float4 v0 = *(float4*)p;
    float4 v1 = *(float4*)(p + 4);
    float m = fmaxf(fmaxf(fmaxf(v0.x, v0.y), fmaxf(v0.z, v0.w)),
                    fmaxf(fmaxf(v1.x, v1.y), fmaxf(v1.z, v1.w)));
    #pragma unroll
    for (int off = 32; off > 0; off >>= 1) m = fmaxf(m, __shfl_xor(m, off));
    v0.x = __expf(v0.x - m); v0.y = __expf(v0.y - m);
    v0.z = __expf(v0.z - m); v0.w = __expf(v0.w - m);
    v1.x = __expf(v1.x - m); v1.y = __expf(v1.y - m);
    v1.z = __expf(v1.z - m); v1.w = __expf(v1.w - m);
    float s = v0.x + v0.y + v0.z + v0.w + v1.x + v1.y + v1.z + v1.w;
    #pragma unroll
    for (int off = 32; off > 0; off >>= 1) s += __shfl_xor(s, off);
    const float inv = 1.0f / s;
    v0.x *= inv; v0.y *= inv; v0.z *= inv; v0.w *= inv;
    v1.x *= inv; v1.y *= inv; v1.z *= inv; v1.w *= inv;
    *(float4*)p = v0;
    *(float4*)(p + 4) = v1;
}

__global__ void transpose_bn(const float* __restrict__ in, float* __restrict__ out)
{
    __shared__ float tile[32][33];
    const int b = blockIdx.z;
    const int n0 = blockIdx.x * 32, e0 = blockIdx.y * 32;
    const float* src = in + (long)b * 512 * 1024;
    float* dst = out + (long)b * 1024 * 512;
    const int tx = threadIdx.x, ty = threadIdx.y;
    for (int i = ty; i < 32; i += 8)
        tile[i][tx] = src[(long)(n0 + i) * 1024 + e0 + tx];
    __syncthreads();
    for (int i = ty; i < 32; i += 8)
        dst[(long)(e0 + i) * 512 + n0 + tx] = tile[tx][i];
}

// ============================ LAUNCH ========================================

extern "C" void kernel_launch(void* const* d_in, const int* in_sizes, int n_in,
                              void* d_out, int out_size, void* d_ws, size_t ws_size,
                              hipStream_t stream)
{
    const float* word = (const float*)d_in[0];  // (8,2048,1024)
    const float* sent = (const float*)d_in[1];  // (8,512,1024)
    const float* W    = (const float*)d_in[2];  // (1024,1024)
    float* out  = (float*)d_out;
    float* comb = out;                              // (8,2048,2048)
    float* gout = out + (long)8 * 2048 * 2048;      // (8,2048,1024)

    const size_t MB = 1ull << 20;

    if (ws_size >= 92 * MB) {
        // -------- fast path --------
        char* w8 = (char*)d_ws;
        unsigned short* word_h = (unsigned short*)(w8);            // 32 MB
        unsigned short* word_l = (unsigned short*)(w8 + 32 * MB);  // 32 MB
        unsigned short* W_h    = (unsigned short*)(w8 + 64 * MB);  // 2 MB
        unsigned short* W_l    = (unsigned short*)(w8 + 66 * MB);  // 2 MB
        unsigned short* sent_h = (unsigned short*)(w8 + 68 * MB);  // 8 MB
        unsigned short* sent_l = (unsigned short*)(w8 + 76 * MB);  // 8 MB
        unsigned short* sentT  = (unsigned short*)(w8 + 84 * MB);  // 8 MB
        // aliases (word_h/word_l dead after GEMM1):
        float*          scores = (float*)(w8);                     // 32 MB
        unsigned short* att    = (unsigned short*)(w8 + 32 * MB);  // 16 MB

        convert_hl<<<16384, 256, 0, stream>>>(word, word_h, word_l);
        convert_hl<<<1024, 256, 0, stream>>>(W, W_h, W_l);
        convert_hl<<<4096, 256, 0, stream>>>(sent, sent_h, sent_l);
        transpose_conv<<<dim3(16, 32, 8), dim3(32, 8), 0, stream>>>(sent, sentT);

        const size_t lds4 = 4 * 128 * 32 * sizeof(unsigned short);  // 32 KB
        const size_t lds2 = 2 * 128 * 32 * sizeof(unsigned short);  // 16 KB

        // GEMM1: w = word @ W^T -> comb[:, :, 0:1024]   (split, all-DMA)
        gemm_fast<M_SPLIT_DMA><<<dim3(128, 8, 1), 256, lds4, stream>>>(
            word_h, word_l, 0L, 1024, W_h, W_l, 0L, 1024,
            comb, 0L, 2048, nullptr, 0L, 0, 1024);

        // GEMM2: scores = w @ sent^T  (split; A converted in-kernel from fp32 comb)
        gemm_fast<M_SPLIT_ACONV><<<dim3(16, 4, 8), 256, lds4, stream>>>(
            comb, nullptr, (long)2048 * 2048, 2048, sent_h, sent_l, (long)512 * 1024, 1024,
            scores, (long)2048 * 512, 512, nullptr, 0L, 0, 1024);

        softmax_bf16<<<4096, 256, 0, stream>>>(scores, att);

        // GEMM3: g = att @ sent -> gout AND comb[:, :, 1024:2048]  (plain, all-DMA)
        gemm_fast<M_PLAIN><<<dim3(16, 8, 8), 256, lds2, stream>>>(
            att, nullptr, (long)2048 * 512, 512, sentT, nullptr, (long)1024 * 512, 512,
            gout, (long)2048 * 1024, 1024, comb + 1024, (long)2048 * 2048, 2048, 512);
    } else {
        // -------- round-1 fallback (48 MB ws) --------
        float* scores = (float*)d_ws;                   // 32 MB
        float* sentT  = scores + (long)8 * 2048 * 512;  // 16 MB
        const size_t lds_split  = 4 * 128 * 40 * sizeof(unsigned short);
        const size_t lds_single = 2 * 128 * 40 * sizeof(unsigned short);

        transpose_bn<<<dim3(16, 32, 8), dim3(32, 8), 0, stream>>>(sent, sentT);
        gemm_bt<true><<<dim3(128, 8, 1), 256, lds_split, stream>>>(
            word, 0L, 1024, W, 0L, 1024, comb, 0L, 2048, nullptr, 0L, 0, 1024);
        gemm_bt<true><<<dim3(16, 4, 8), 256, lds_split, stream>>>(
            comb, (long)2048 * 2048, 2048, sent, (long)512 * 1024, 1024,
            scores, (long)2048 * 512, 512, nullptr, 0L, 0, 1024);
        softmax_rows<<<4096, 256, 0, stream>>>(scores);
        gemm_bt<false><<<dim3(16, 8, 8), 256, lds_single, stream>>>(
            scores, (long)2048 * 512, 512, sentT, (long)1024 * 512, 512,
            gout, (long)2048 * 1024, 1024, comb + 1024, (long)2048 * 2048, 2048, 512);
    }
}

// Round 3
// 457.888 us; speedup vs baseline: 1.2446x; 1.0390x over previous
//
#include <hip/hip_runtime.h>

typedef __attribute__((ext_vector_type(8))) short short8;
typedef __attribute__((ext_vector_type(4))) float f32x4;
typedef __attribute__((ext_vector_type(4))) unsigned short u16x4;

typedef const __attribute__((address_space(1))) void* gas_t;
typedef __attribute__((address_space(3))) void* las_t;

__device__ inline unsigned short f2bf(float x) {
    union { float f; unsigned u; } v; v.f = x;
    unsigned r = v.u + 0x7fffu + ((v.u >> 16) & 1u);
    return (unsigned short)(r >> 16);
}
__device__ inline float bf2f(unsigned short h) {
    union { unsigned u; float f; } v; v.u = ((unsigned)h) << 16;
    return v.f;
}

// ============================ PREP KERNELS ==================================

// fp32 -> bf16 hi/lo, elementwise (4 elems/thread)
__global__ __launch_bounds__(256)
void convert_hl(const float* __restrict__ x, unsigned short* __restrict__ h,
                unsigned short* __restrict__ l)
{
    const long i = ((long)blockIdx.x * 256 + threadIdx.x) * 4;
    const float4 v = *(const float4*)(x + i);
    u16x4 hh, ll;
    hh[0] = f2bf(v.x); hh[1] = f2bf(v.y); hh[2] = f2bf(v.z); hh[3] = f2bf(v.w);
    ll[0] = f2bf(v.x - bf2f(hh[0])); ll[1] = f2bf(v.y - bf2f(hh[1]));
    ll[2] = f2bf(v.z - bf2f(hh[2])); ll[3] = f2bf(v.w - bf2f(hh[3]));
    *(u16x4*)(h + i) = hh;
    *(u16x4*)(l + i) = ll;
}

// W (1024x1024 fp32) -> W_h (bf16, same layout) + Wt_h/Wt_l (transposed hi/lo)
__global__ void prep_W(const float* __restrict__ W, unsigned short* __restrict__ W_h,
                       unsigned short* __restrict__ Wt_h, unsigned short* __restrict__ Wt_l)
{
    __shared__ float tile[32][33];
    const int e0 = blockIdx.x * 32, f0 = blockIdx.y * 32;
    const int tx = threadIdx.x, ty = threadIdx.y;
    for (int i = ty; i < 32; i += 8) {
        const float v = W[(long)(e0 + i) * 1024 + f0 + tx];
        tile[i][tx] = v;
        W_h[(long)(e0 + i) * 1024 + f0 + tx] = f2bf(v);
    }
    __syncthreads();
    for (int i = ty; i < 32; i += 8) {
        const float v = tile[tx][i];  // = W[e0+tx][f0+i]
        const unsigned short h = f2bf(v);
        Wt_h[(long)(f0 + i) * 1024 + e0 + tx] = h;
        Wt_l[(long)(f0 + i) * 1024 + e0 + tx] = f2bf(v - bf2f(h));
    }
}

// sent (8x512x1024 fp32) -> sent_h/sent_l (same layout) + sentT (8x1024x512 bf16)
__global__ void prep_sent(const float* __restrict__ sent,
                          unsigned short* __restrict__ s_h, unsigned short* __restrict__ s_l,
                          unsigned short* __restrict__ sT)
{
    __shared__ float tile[32][33];
    const int b = blockIdx.z;
    const int n0 = blockIdx.x * 32, e0 = blockIdx.y * 32;
    const float* src = sent + (long)b * 512 * 1024;
    const int tx = threadIdx.x, ty = threadIdx.y;
    for (int i = ty; i < 32; i += 8) {
        const float v = src[(long)(n0 + i) * 1024 + e0 + tx];
        tile[i][tx] = v;
        const unsigned short h = f2bf(v);
        s_h[(long)b * 512 * 1024 + (long)(n0 + i) * 1024 + e0 + tx] = h;
        s_l[(long)b * 512 * 1024 + (long)(n0 + i) * 1024 + e0 + tx] = f2bf(v - bf2f(h));
    }
    __syncthreads();
    for (int i = ty; i < 32; i += 8)
        sT[(long)b * 1024 * 512 + (long)(e0 + i) * 512 + n0 + tx] = f2bf(tile[tx][i]);
}

// Row softmax over 512 cols: read fp32 scores (row stride lds_), write bf16 att.
__global__ __launch_bounds__(256)
void softmax_bf16(const float* __restrict__ S, int ldS, unsigned short* __restrict__ att)
{
    const int wave = threadIdx.x >> 6, lane = threadIdx.x & 63;
    const long row = (long)blockIdx.x * 4 + wave;
    const float* p = S + row * ldS + lane * 8;
    float4 v0 = *(const float4*)p;
    float4 v1 = *(const float4*)(p + 4);
    float m = fmaxf(fmaxf(fmaxf(v0.x, v0.y), fmaxf(v0.z, v0.w)),
                    fmaxf(fmaxf(v1.x, v1.y), fmaxf(v1.z, v1.w)));
    #pragma unroll
    for (int off = 32; off > 0; off >>= 1) m = fmaxf(m, __shfl_xor(m, off));
    v0.x = __expf(v0.x - m); v0.y = __expf(v0.y - m);
    v0.z = __expf(v0.z - m); v0.w = __expf(v0.w - m);
    v1.x = __expf(v1.x - m); v1.y = __expf(v1.y - m);
    v1.z = __expf(v1.z - m); v1.w = __expf(v1.w - m);
    float s = v0.x + v0.y + v0.z + v0.w + v1.x + v1.y + v1.z + v1.w;
    #pragma unroll
    for (int off = 32; off > 0; off >>= 1) s += __shfl_xor(s, off);
    const float inv = 1.0f / s;
    u16x4 a0, a1;
    a0[0] = f2bf(v0.x * inv); a0[1] = f2bf(v0.y * inv);
    a0[2] = f2bf(v0.z * inv); a0[3] = f2bf(v0.w * inv);
    a1[0] = f2bf(v1.x * inv); a1[1] = f2bf(v1.y * inv);
    a1[2] = f2bf(v1.z * inv); a1[3] = f2bf(v1.w * inv);
    unsigned short* o = att + row * 512 + lane * 8;
    *(u16x4*)o = a0;
    *(u16x4*)(o + 4) = a1;
}

// ============================ GEMM (m97 structure) ==========================
// C = A * B^T. 128x128 tile, BK=32, 4 waves, 4x4 grid of 16x16x32 bf16 MFMA.
// All operands pre-converted bf16 (hi[,lo]); staging via global_load_lds w=16.
// EPI_HL: write bf16 hi/lo pair instead of fp32 C (for the V intermediate).
template<bool SPLIT, bool EPI_HL>
__global__ __launch_bounds__(256, 2)
void gemm_k(const unsigned short* __restrict__ Ahg, const unsigned short* __restrict__ Alg,
            long sA, int lda,
            const unsigned short* __restrict__ Bhg, const unsigned short* __restrict__ Blg,
            long sB, int ldb,
            float* __restrict__ C, long sC, int ldc,
            float* __restrict__ C2, long sC2, int ldc2,
            unsigned short* __restrict__ Oh, unsigned short* __restrict__ Ol,
            long sO, int ldo,
            int K)
{
    extern __shared__ unsigned short lds[];
    unsigned short* AhL = lds;                 // 128*32 bf16 = 8 KB each
    unsigned short* BhL = lds + 128 * 32;
    unsigned short* AlL = SPLIT ? lds + 2 * 128 * 32 : nullptr;
    unsigned short* BlL = SPLIT ? lds + 3 * 128 * 32 : nullptr;

    const int tid = threadIdx.x;
    const long bz = blockIdx.z;
    const long m0 = (long)blockIdx.x * 128;
    const long n0 = (long)blockIdx.y * 128;

    const int lane = tid & 63, wave = tid >> 6;
    const int wm = (wave >> 1) * 64, wn = (wave & 1) * 64;
    const int fr = lane & 15, kq = lane >> 4, k0 = kq * 8;

    // DMA staging coords: lane covers row (lane>>2), 16B chunk (lane&3)
    const int drow = lane >> 2, dcol = (lane & 3) * 8;

    const unsigned short* Ah = Ahg + bz * sA;
    const unsigned short* Bh = Bhg + bz * sB;
    const unsigned short* Al = SPLIT ? Alg + bz * sA : nullptr;
    const unsigned short* Bl = SPLIT ? Blg + bz * sB : nullptr;

    f32x4 acc[4][4] = {};

    for (int kb = 0; kb < K; kb += 32) {
        #pragma unroll
        for (int r = 0; r < 2; ++r) {
            const int rb = r * 64 + wave * 16;
            __builtin_amdgcn_global_load_lds(
                (gas_t)(Ah + (m0 + rb + drow) * (long)lda + kb + dcol),
                (las_t)(AhL + rb * 32), 16, 0, 0);
            __builtin_amdgcn_global_load_lds(
                (gas_t)(Bh + (n0 + rb + drow) * (long)ldb + kb + dcol),
                (las_t)(BhL + rb * 32), 16, 0, 0);
            if constexpr (SPLIT) {
                __builtin_amdgcn_global_load_lds(
                    (gas_t)(Al + (m0 + rb + drow) * (long)lda + kb + dcol),
                    (las_t)(AlL + rb * 32), 16, 0, 0);
                __builtin_amdgcn_global_load_lds(
                    (gas_t)(Bl + (n0 + rb + drow) * (long)ldb + kb + dcol),
                    (las_t)(BlL + rb * 32), 16, 0, 0);
            }
        }
        __syncthreads();

        short8 af[4], bfr[4], alf[4], blf[4];
        #pragma unroll
        for (int t = 0; t < 4; ++t) {
            af[t]  = *(const short8*)(AhL + (wm + t * 16 + fr) * 32 + k0);
            bfr[t] = *(const short8*)(BhL + (wn + t * 16 + fr) * 32 + k0);
            if constexpr (SPLIT) {
                alf[t] = *(const short8*)(AlL + (wm + t * 16 + fr) * 32 + k0);
                blf[t] = *(const short8*)(BlL + (wn + t * 16 + fr) * 32 + k0);
            }
        }
        #pragma unroll
        for (int mt = 0; mt < 4; ++mt)
            #pragma unroll
            for (int nt = 0; nt < 4; ++nt) {
                acc[mt][nt] = __builtin_amdgcn_mfma_f32_16x16x32_bf16(af[mt], bfr[nt], acc[mt][nt], 0, 0, 0);
                if constexpr (SPLIT) {
                    acc[mt][nt] = __builtin_amdgcn_mfma_f32_16x16x32_bf16(alf[mt], bfr[nt], acc[mt][nt], 0, 0, 0);
                    acc[mt][nt] = __builtin_amdgcn_mfma_f32_16x16x32_bf16(af[mt], blf[nt], acc[mt][nt], 0, 0, 0);
                }
            }
        __syncthreads();
    }

    // epilogue: C row = kq*4+i, col = lane&15 (verified C/D layout)
    #pragma unroll
    for (int mt = 0; mt < 4; ++mt) {
        const long rowb = m0 + wm + mt * 16 + kq * 4;
        #pragma unroll
        for (int nt = 0; nt < 4; ++nt) {
            const long col = n0 + wn + nt * 16 + fr;
            #pragma unroll
            for (int i = 0; i < 4; ++i) {
                const float v = acc[mt][nt][i];
                if constexpr (EPI_HL) {
                    const unsigned short h = f2bf(v);
                    Oh[bz * sO + (rowb + i) * ldo + col] = h;
                    Ol[bz * sO + (rowb + i) * ldo + col] = f2bf(v - bf2f(h));
                } else {
                    C[bz * sC + (rowb + i) * ldc + col] = v;
                    if (C2) C2[bz * sC2 + (rowb + i) * ldc2 + col] = v;
                }
            }
        }
    }
}

// ============================ FALLBACK PATH (round-1) ========================

template<bool SPLIT>
__global__ __launch_bounds__(256, 2)
void gemm_bt(const float* __restrict__ A, long sA, int lda,
             const float* __restrict__ B, long sB, int ldb,
             float* __restrict__ C, long sC, int ldc,
             float* __restrict__ C2, long sC2, int ldc2,
             int K)
{
    constexpr int LDS_S = 40;
    extern __shared__ unsigned short lds[];
    unsigned short* Ah = lds;
    unsigned short* Bh = lds + 128 * LDS_S;
    unsigned short* Al = SPLIT ? (lds + 2 * 128 * LDS_S) : nullptr;
    unsigned short* Bl = SPLIT ? (lds + 3 * 128 * LDS_S) : nullptr;

    const int tid = threadIdx.x;
    const int bz = blockIdx.z;
    A += (long)bz * sA; B += (long)bz * sB; C += (long)bz * sC;
    if (C2) C2 += (long)bz * sC2;
    const long m0 = (long)blockIdx.x * 128;
    const long n0 = (long)blockIdx.y * 128;

    const int lane = tid & 63, wave = tid >> 6;
    const int wm = (wave >> 1) * 64, wn = (wave & 1) * 64;
    const int fr = lane & 15, kq = lane >> 4, k0 = kq * 8;
    const int sc4 = (tid & 7) * 4;
    const int sr  = tid >> 3;

    f32x4 acc[4][4] = {};

    for (int kb = 0; kb < K; kb += 32) {
        #pragma unroll
        for (int p = 0; p < 4; ++p) {
            const int row = p * 32 + sr;
            const float4 va = *(const float4*)(A + (m0 + row) * lda + kb + sc4);
            const float4 vb = *(const float4*)(B + (n0 + row) * ldb + kb + sc4);
            u16x4 ah; ah[0] = f2bf(va.x); ah[1] = f2bf(va.y); ah[2] = f2bf(va.z); ah[3] = f2bf(va.w);
            u16x4 bh; bh[0] = f2bf(vb.x); bh[1] = f2bf(vb.y); bh[2] = f2bf(vb.z); bh[3] = f2bf(vb.w);
            *(u16x4*)(Ah + row * LDS_S + sc4) = ah;
            *(u16x4*)(Bh + row * LDS_S + sc4) = bh;
            if constexpr (SPLIT) {
                u16x4 al; al[0] = f2bf(va.x - bf2f(ah[0])); al[1] = f2bf(va.y - bf2f(ah[1]));
                          al[2] = f2bf(va.z - bf2f(ah[2])); al[3] = f2bf(va.w - bf2f(ah[3]));
                u16x4 bl; bl[0] = f2bf(vb.x - bf2f(bh[0])); bl[1] = f2bf(vb.y - bf2f(bh[1]));
                          bl[2] = f2bf(vb.z - bf2f(bh[2])); bl[3] = f2bf(vb.w - bf2f(bh[3]));
                *(u16x4*)(Al + row * LDS_S + sc4) = al;
                *(u16x4*)(Bl + row * LDS_S + sc4) = bl;
            }
        }
        __syncthreads();

        short8 af[4], bfr[4], alf[4], blf[4];
        #pragma unroll
        for (int t = 0; t < 4; ++t) {
            af[t]  = *(const short8*)(Ah + (wm + t * 16 + fr) * LDS_S + k0);
            bfr[t] = *(const short8*)(Bh + (wn + t * 16 + fr) * LDS_S + k0);
            if constexpr (SPLIT) {
                alf[t] = *(const short8*)(Al + (wm + t * 16 + fr) * LDS_S + k0);
                blf[t] = *(const short8*)(Bl + (wn + t * 16 + fr) * LDS_S + k0);
            }
        }
        #pragma unroll
        for (int mt = 0; mt < 4; ++mt)
            #pragma unroll
            for (int nt = 0; nt < 4; ++nt) {
                acc[mt][nt] = __builtin_amdgcn_mfma_f32_16x16x32_bf16(af[mt], bfr[nt], acc[mt][nt], 0, 0, 0);
                if constexpr (SPLIT) {
                    acc[mt][nt] = __builtin_amdgcn_mfma_f32_16x16x32_bf16(alf[mt], bfr[nt], acc[mt][nt], 0, 0, 0);
                    acc[mt][nt] = __builtin_amdgcn_mfma_f32_16x16x32_bf16(af[mt], blf[nt], acc[mt][nt], 0, 0, 0);
                }
            }
        __syncthreads();
    }

    #pragma unroll
    for (int mt = 0; mt < 4; ++mt) {
        const long rowb = m0 + wm + mt * 16 + kq * 4;
        #pragma unroll
        for (int nt = 0; nt < 4; ++nt) {
            const long col = n0 + wn + nt * 16 + fr;
            #pragma unroll
            for (int i = 0; i < 4; ++i) {
                C[(rowb + i) * ldc + col] = acc[mt][nt][i];
                if (C2) C2[(rowb + i) * ldc2 + col] = acc[mt][nt][i];
            }
        }
    }
}

__global__ __launch_bounds__(256)
void softmax_rows(float* __restrict__ S)
{
    const int wave = threadIdx.x >> 6, lane = threadIdx.x & 63;
    const long row = (long)blockIdx.x * 4 + wave;
    float* p = S + row * 512 + lane * 8;
    float4 v0 = *(float4*)p;
    float4 v1 = *(float4*)(p + 4);
    float m = fmaxf(fmaxf(fmaxf(v0.x, v0.y), fmaxf(v0.z, v0.w)),
                    fmaxf(fmaxf(v1.x, v1.y), fmaxf(v1.z, v1.w)));
    #pragma unroll
    for (int off = 32; off > 0; off >>= 1) m = fmaxf(m, __shfl_xor(m, off));
    v0.x = __expf(v0.x - m); v0.y = __expf(v0.y - m);
    v0.z = __expf(v0.z - m); v0.w = __expf(v0.w - m);
    v1.x = __expf(v1.x - m); v1.y = __expf(v1.y - m);
    v1.z = __expf(v1.z - m); v1.w = __expf(v1.w - m);
    float s = v0.x + v0.y + v0.z + v0.w + v1.x + v1.y + v1.z + v1.w;
    #pragma unroll
    for (int off = 32; off > 0; off >>= 1) s += __shfl_xor(s, off);
    const float inv = 1.0f / s;
    v0.x *= inv; v0.y *= inv; v0.z *= inv; v0.w *= inv;
    v1.x *= inv; v1.y *= inv; v1.z *= inv; v1.w *= inv;
    *(float4*)p = v0;
    *(float4*)(p + 4) = v1;
}

__global__ void transpose_bn(const float* __restrict__ in, float* __restrict__ out)
{
    __shared__ float tile[32][33];
    const int b = blockIdx.z;
    const int n0 = blockIdx.x * 32, e0 = blockIdx.y * 32;
    const float* src = in + (long)b * 512 * 1024;
    float* dst = out + (long)b * 1024 * 512;
    const int tx = threadIdx.x, ty = threadIdx.y;
    for (int i = ty; i < 32; i += 8)
        tile[i][tx] = src[(long)(n0 + i) * 1024 + e0 + tx];
    __syncthreads();
    for (int i = ty; i < 32; i += 8)
        dst[(long)(e0 + i) * 512 + n0 + tx] = tile[tx][i];
}

// ============================ LAUNCH ========================================

extern "C" void kernel_launch(void* const* d_in, const int* in_sizes, int n_in,
                              void* d_out, int out_size, void* d_ws, size_t ws_size,
                              hipStream_t stream)
{
    const float* word = (const float*)d_in[0];  // (8,2048,1024)
    const float* sent = (const float*)d_in[1];  // (8,512,1024)
    const float* W    = (const float*)d_in[2];  // (1024,1024)
    float* out  = (float*)d_out;
    float* comb = out;                              // (8,2048,2048)
    float* gout = out + (long)8 * 2048 * 2048;      // (8,2048,1024)

    const size_t MB = 1ull << 20;

    if (ws_size >= 110 * MB) {
        // -------- fast path: V = sent@W re-decomposition --------
        char* w8 = (char*)d_ws;
        unsigned short* word_h = (unsigned short*)(w8);             // 32 MB [0,32)
        unsigned short* word_l = (unsigned short*)(w8 + 32 * MB);   // 32 MB [32,64)
        unsigned short* V_h    = (unsigned short*)(w8 + 64 * MB);   //  8 MB [64,72)
        unsigned short* V_l    = (unsigned short*)(w8 + 72 * MB);   //  8 MB [72,80)
        unsigned short* sentT  = (unsigned short*)(w8 + 80 * MB);   //  8 MB [80,88)
        unsigned short* sent_h = (unsigned short*)(w8 + 88 * MB);   //  8 MB [88,96)  dead after V-GEMM
        unsigned short* sent_l = (unsigned short*)(w8 + 96 * MB);   //  8 MB [96,104) dead after V-GEMM
        unsigned short* W_h    = (unsigned short*)(w8 + 104 * MB);  //  2 MB [104,106) dead after w-GEMM
        unsigned short* Wt_h   = (unsigned short*)(w8 + 106 * MB);  //  2 MB [106,108) dead after V-GEMM
        unsigned short* Wt_l   = (unsigned short*)(w8 + 108 * MB);  //  2 MB [108,110) dead after V-GEMM
        unsigned short* att    = (unsigned short*)(w8 + 88 * MB);   // 16 MB over sent_h/l (post-V)
        float* scores = comb + 1024;  // scores live in comb[:, :, 1024:2048] (ld 2048)

        convert_hl<<<16384, 256, 0, stream>>>(word, word_h, word_l);
        prep_W<<<dim3(32, 32), dim3(32, 8), 0, stream>>>(W, W_h, Wt_h, Wt_l);
        prep_sent<<<dim3(16, 32, 8), dim3(32, 8), 0, stream>>>(sent, sent_h, sent_l, sentT);

        const size_t lds4 = 4 * 128 * 32 * sizeof(unsigned short);  // 32 KB
        const size_t lds2 = 2 * 128 * 32 * sizeof(unsigned short);  // 16 KB

        // w = word @ W^T (PLAIN bf16) -> comb[:, :, 0:1024]
        gemm_k<false, false><<<dim3(128, 8, 1), 256, lds2, stream>>>(
            word_h, nullptr, 0L, 1024, W_h, nullptr, 0L, 1024,
            comb, 0L, 2048, nullptr, 0L, 0, nullptr, nullptr, 0L, 0, 1024);

        // V = sent @ W (SPLIT), batches merged in M (4096x1024), B=Wt shared
        //   epilogue writes V_h/V_l bf16 directly
        gemm_k<true, true><<<dim3(32, 8, 1), 256, lds4, stream>>>(
            sent_h, sent_l, 0L, 1024, Wt_h, Wt_l, 0L, 1024,
            nullptr, 0L, 0, nullptr, 0L, 0, V_h, V_l, 0L, 1024, 1024);

        // scores = word @ V^T (SPLIT) -> comb[:, :, 1024:2048]
        gemm_k<true, false><<<dim3(16, 4, 8), 256, lds4, stream>>>(
            word_h, word_l, (long)2048 * 1024, 1024, V_h, V_l, (long)512 * 1024, 1024,
            scores, (long)2048 * 2048, 2048, nullptr, 0L, 0, nullptr, nullptr, 0L, 0, 1024);

        // softmax over 512 cols (rows stride 2048 inside comb) -> bf16 att
        softmax_bf16<<<4096, 256, 0, stream>>>(scores, 2048, att);

        // g = att @ sent (PLAIN) -> gout AND comb[:, :, 1024:2048]
        gemm_k<false, false><<<dim3(16, 8, 8), 256, lds2, stream>>>(
            att, nullptr, (long)2048 * 512, 512, sentT, nullptr, (long)1024 * 512, 512,
            gout, (long)2048 * 1024, 1024, comb + 1024, (long)2048 * 2048, 2048,
            nullptr, nullptr, 0L, 0, 512);
    } else {
        // -------- round-1 fallback (48 MB ws) --------
        float* scores = (float*)d_ws;                   // 32 MB
        float* sentT  = scores + (long)8 * 2048 * 512;  // 16 MB
        const size_t lds_split  = 4 * 128 * 40 * sizeof(unsigned short);
        const size_t lds_single = 2 * 128 * 40 * sizeof(unsigned short);

        transpose_bn<<<dim3(16, 32, 8), dim3(32, 8), 0, stream>>>(sent, sentT);
        gemm_bt<true><<<dim3(128, 8, 1), 256, lds_split, stream>>>(
            word, 0L, 1024, W, 0L, 1024, comb, 0L, 2048, nullptr, 0L, 0, 1024);
        gemm_bt<true><<<dim3(16, 4, 8), 256, lds_split, stream>>>(
            comb, (long)2048 * 2048, 2048, sent, (long)512 * 1024, 1024,
            scores, (long)2048 * 512, 512, nullptr, 0L, 0, 1024);
        softmax_rows<<<4096, 256, 0, stream>>>(scores);
        gemm_bt<false><<<dim3(16, 8, 8), 256, lds_single, stream>>>(
            scores, (long)2048 * 512, 512, sentT, (long)1024 * 512, 512,
            gout, (long)2048 * 1024, 1024, comb + 1024, (long)2048 * 2048, 2048, 512);
    }
}